// Round 1
// baseline (311.974 us; speedup 1.0000x reference)
//
#include <hip/hip_runtime.h>

typedef __attribute__((ext_vector_type(8))) _Float16 half8;
typedef __attribute__((ext_vector_type(4))) _Float16 half4v;
typedef __attribute__((ext_vector_type(4))) float floatx4;

// dims
#define NB 128   // batch
#define NN 64    // particles
#define NV 14    // vertices
#define PP 32    // particle features
#define SS 14    // vertex features
#define HH 128   // hidden
#define DE 64    // edge embed
#define DO 64    // out embed
#define NCLS 5

// WT element offsets (fp16 units)
#define OFF_W2T   0
#define OFF_W3T   16384
#define OFF_W2PVT 24576
#define OFF_W3PVT 40960
#define OFF_FO1T  49152
#define OFF_FO2T  69632
#define OFF_FO3T  86016

// ---------------- K0: per-node layer-1 terms + weight transpose/fp16 ----------------
__global__ __launch_bounds__(256) void k0_prep(
    const float* __restrict__ x, const float* __restrict__ y,
    const float* __restrict__ fr1_w, const float* __restrict__ fr1pv_w,
    const float* __restrict__ fr2_w, const float* __restrict__ fr3_w,
    const float* __restrict__ fr2pv_w, const float* __restrict__ fr3pv_w,
    const float* __restrict__ fo1_w, const float* __restrict__ fo2_w,
    const float* __restrict__ fo3_w,
    float* __restrict__ A1, float* __restrict__ B1,
    float* __restrict__ A1pv, float* __restrict__ B1pv,
    _Float16* __restrict__ WT) {
  int blk = blockIdx.x;
  int tid = threadIdx.x;
  if (blk < NB) {
    __shared__ float sxT[NN * PP];    // xT[n][p]
    __shared__ float syT[NV * SS];    // yT[v][s]
    int b = blk;
    for (int i = tid; i < NN * PP; i += 256) {
      int p = i >> 6, n = i & 63;     // i = p*64+n, coalesced read
      sxT[n * PP + p] = x[b * (PP * NN) + i];
    }
    for (int i = tid; i < SS * NV; i += 256) {
      int s = i / NV, v = i - s * NV;
      syT[v * SS + s] = y[b * (SS * NV) + i];
    }
    __syncthreads();
    // A1 = xT @ fr1_w[:32], B1 = xT @ fr1_w[32:], A1pv = xT @ fr1pv_w[:32]
    for (int m = 0; m < 3; m++) {
      const float* w = (m == 0) ? fr1_w : (m == 1) ? (fr1_w + 32 * HH) : fr1pv_w;
      float* outp = (m == 0) ? A1 : (m == 1) ? B1 : A1pv;
      for (int o = tid; o < NN * 32; o += 256) {
        int n = o >> 5, jc = o & 31;  // jc: 4-col chunk
        float4 acc = {0.f, 0.f, 0.f, 0.f};
        const float* xr = &sxT[n * PP];
#pragma unroll 8
        for (int k = 0; k < PP; k++) {
          float xv = xr[k];
          float4 wv = ((const float4*)w)[k * 32 + jc];
          acc.x += xv * wv.x; acc.y += xv * wv.y;
          acc.z += xv * wv.z; acc.w += xv * wv.w;
        }
        ((float4*)outp)[(b * NN + n) * 32 + jc] = acc;
      }
    }
    // B1pv = yT @ fr1pv_w[32:46]
    for (int o = tid; o < NV * 32; o += 256) {
      int v = o >> 5, jc = o & 31;
      float4 acc = {0.f, 0.f, 0.f, 0.f};
#pragma unroll
      for (int s = 0; s < SS; s++) {
        float yv = syT[v * SS + s];
        float4 wv = ((const float4*)(fr1pv_w + 32 * HH))[s * 32 + jc];
        acc.x += yv * wv.x; acc.y += yv * wv.y;
        acc.z += yv * wv.z; acc.w += yv * wv.w;
      }
      ((float4*)B1pv)[(b * NV + v) * 32 + jc] = acc;
    }
  } else {
    // transpose + fp16 convert weights: dst[n][k] = src[k][n]
    int wid = blk - NB;
    const float* src; int K, N; _Float16* dst;
    switch (wid) {
      case 0: src = fr2_w;   K = 128; N = 128; dst = WT + OFF_W2T;   break;
      case 1: src = fr3_w;   K = 128; N = 64;  dst = WT + OFF_W3T;   break;
      case 2: src = fr2pv_w; K = 128; N = 128; dst = WT + OFF_W2PVT; break;
      case 3: src = fr3pv_w; K = 128; N = 64;  dst = WT + OFF_W3PVT; break;
      case 4: src = fo1_w;   K = 160; N = 128; dst = WT + OFF_FO1T;  break;
      case 5: src = fo2_w;   K = 128; N = 128; dst = WT + OFF_FO2T;  break;
      default: src = fo3_w;  K = 128; N = 64;  dst = WT + OFF_FO3T;  break;
    }
    int tot = K * N;
    for (int i = tid; i < tot; i += 256) {
      int n = i / K, k = i - n * K;
      dst[i] = (_Float16)src[k * N + n];
    }
  }
}

// ---------------- K1: pp edges, fused layer2+3 + segmented reduce ----------------
// block = (b, receiver r); M=64 rows (63 edges + 1 pad), 4 waves x 16-row Mtile
__global__ __launch_bounds__(256) void k1_pp(
    const float* __restrict__ A1, const float* __restrict__ B1,
    const float* __restrict__ fr1_b, const float* __restrict__ fr2_b,
    const float* __restrict__ fr3_b,
    const _Float16* __restrict__ W2T, const _Float16* __restrict__ W3T,
    float* __restrict__ Ebar) {
  __shared__ _Float16 sW2[128 * 136];   // padded pitch: conflict-free frags
  __shared__ _Float16 sH[64 * 136];     // h1, then h2 in place
  __shared__ float sA1[128];
  __shared__ float sEb[64];
  int tid = threadIdx.x;
  int b = blockIdx.x >> 6, r = blockIdx.x & 63;
  if (tid < 64) sEb[tid] = 0.f;
  if (tid < 128) sA1[tid] = A1[(b * NN + r) * HH + tid] + fr1_b[tid];
  for (int i = tid; i < 128 * 16; i += 256) {
    int row = i >> 4, c = i & 15;
    *(uint4*)(&sW2[row * 136 + c * 8]) = *(const uint4*)(&W2T[row * 128 + c * 8]);
  }
  __syncthreads();
  // h1 = relu(A1[r] + B1[s] + b1), row 63 = pad -> 0
  for (int i = tid; i < 64 * 32; i += 256) {
    int row = i >> 5, jc = i & 31;
    int j4 = jc * 4;
    float a0 = 0.f, a1 = 0.f, a2f = 0.f, a3 = 0.f;
    if (row < 63) {
      int s = row + (row >= r ? 1 : 0);
      float4 bv = ((const float4*)B1)[(b * NN + s) * 32 + jc];
      a0 = sA1[j4 + 0] + bv.x; a1 = sA1[j4 + 1] + bv.y;
      a2f = sA1[j4 + 2] + bv.z; a3 = sA1[j4 + 3] + bv.w;
    }
    half4v hv;
    hv[0] = (_Float16)fmaxf(a0, 0.f); hv[1] = (_Float16)fmaxf(a1, 0.f);
    hv[2] = (_Float16)fmaxf(a2f, 0.f); hv[3] = (_Float16)fmaxf(a3, 0.f);
    *(half4v*)(&sH[row * 136 + j4]) = hv;
  }
  __syncthreads();
  int lane = tid & 63, wv = tid >> 6;
  int q = lane >> 4, c = lane & 15;
  int mbase = wv * 16;
  // layer2: h2 = relu(h1 @ W2 + b2)
  half8 afr[4];
#pragma unroll
  for (int ks = 0; ks < 4; ks++)
    afr[ks] = *(const half8*)(&sH[(mbase + c) * 136 + ks * 32 + q * 8]);
#pragma unroll
  for (int nt = 0; nt < 8; nt++) {
    floatx4 acc = {0.f, 0.f, 0.f, 0.f};
#pragma unroll
    for (int ks = 0; ks < 4; ks++) {
      half8 bfr = *(const half8*)(&sW2[(nt * 16 + c) * 136 + ks * 32 + q * 8]);
      acc = __builtin_amdgcn_mfma_f32_16x16x32_f16(afr[ks], bfr, acc, 0, 0, 0);
    }
    int col = nt * 16 + c;
    float bb = fr2_b[col];
#pragma unroll
    for (int rg = 0; rg < 4; rg++) {
      int row = mbase + q * 4 + rg;
      sH[row * 136 + col] = (_Float16)fmaxf(acc[rg] + bb, 0.f);  // own rows only
    }
  }
  // layer3: e = relu(h2 @ W3 + b3); W3 frags straight from global (L1-hot)
  half8 a2[4];
#pragma unroll
  for (int ks = 0; ks < 4; ks++)
    a2[ks] = *(const half8*)(&sH[(mbase + c) * 136 + ks * 32 + q * 8]);
#pragma unroll
  for (int nt = 0; nt < 4; nt++) {
    floatx4 acc = {0.f, 0.f, 0.f, 0.f};
#pragma unroll
    for (int ks = 0; ks < 4; ks++) {
      half8 bfr = *(const half8*)(&W3T[(nt * 16 + c) * 128 + ks * 32 + q * 8]);
      acc = __builtin_amdgcn_mfma_f32_16x16x32_f16(a2[ks], bfr, acc, 0, 0, 0);
    }
    int col = nt * 16 + c;
    float bb = fr3_b[col];
    float sum = 0.f;
#pragma unroll
    for (int rg = 0; rg < 4; rg++) {
      int row = mbase + q * 4 + rg;
      float e = fmaxf(acc[rg] + bb, 0.f);
      sum += (row < 63) ? e : 0.f;   // drop pad row
    }
    sum += __shfl_xor(sum, 16);
    sum += __shfl_xor(sum, 32);
    if (lane < 16) atomicAdd(&sEb[col], sum);
  }
  __syncthreads();
  if (tid < 64) Ebar[(b * NN + r) * DE + tid] = sEb[tid];
}

// ---------------- K2: pv edges, block = (b, 4 k-nodes) -> 56 rows (pad to 64) ----------------
__global__ __launch_bounds__(256) void k2_pv(
    const float* __restrict__ A1pv, const float* __restrict__ B1pv,
    const float* __restrict__ fr1pv_b, const float* __restrict__ fr2pv_b,
    const float* __restrict__ fr3pv_b,
    const _Float16* __restrict__ W2T, const _Float16* __restrict__ W3T,
    float* __restrict__ Ebar) {
  __shared__ _Float16 sW2[128 * 136];
  __shared__ _Float16 sH[64 * 136];
  __shared__ float sA[4 * 128];
  __shared__ float sB[14 * 128];
  __shared__ float sEacc[4 * 64];
  int tid = threadIdx.x;
  int b = blockIdx.x >> 4, kg = blockIdx.x & 15;
  int k0 = kg * 4;
  if (tid < 256) sEacc[tid] = 0.f;
  for (int i = tid; i < 512; i += 256) {
    int kl = i >> 7, j = i & 127;
    sA[i] = A1pv[(b * NN + k0 + kl) * HH + j] + fr1pv_b[j];
  }
  for (int i = tid; i < NV * 128; i += 256)
    sB[i] = B1pv[b * NV * HH + i];
  for (int i = tid; i < 128 * 16; i += 256) {
    int row = i >> 4, c = i & 15;
    *(uint4*)(&sW2[row * 136 + c * 8]) = *(const uint4*)(&W2T[row * 128 + c * 8]);
  }
  __syncthreads();
  for (int i = tid; i < 64 * 32; i += 256) {
    int row = i >> 5, jc = i & 31;
    int j4 = jc * 4;
    float a0 = 0.f, a1 = 0.f, a2f = 0.f, a3 = 0.f;
    if (row < 56) {
      int kl = row / 14;
      int v = row - kl * 14;
      a0 = sA[kl * 128 + j4 + 0] + sB[v * 128 + j4 + 0];
      a1 = sA[kl * 128 + j4 + 1] + sB[v * 128 + j4 + 1];
      a2f = sA[kl * 128 + j4 + 2] + sB[v * 128 + j4 + 2];
      a3 = sA[kl * 128 + j4 + 3] + sB[v * 128 + j4 + 3];
    }
    half4v hv;
    hv[0] = (_Float16)fmaxf(a0, 0.f); hv[1] = (_Float16)fmaxf(a1, 0.f);
    hv[2] = (_Float16)fmaxf(a2f, 0.f); hv[3] = (_Float16)fmaxf(a3, 0.f);
    *(half4v*)(&sH[row * 136 + j4]) = hv;
  }
  __syncthreads();
  int lane = tid & 63, wv = tid >> 6;
  int q = lane >> 4, c = lane & 15;
  int mbase = wv * 16;
  half8 afr[4];
#pragma unroll
  for (int ks = 0; ks < 4; ks++)
    afr[ks] = *(const half8*)(&sH[(mbase + c) * 136 + ks * 32 + q * 8]);
#pragma unroll
  for (int nt = 0; nt < 8; nt++) {
    floatx4 acc = {0.f, 0.f, 0.f, 0.f};
#pragma unroll
    for (int ks = 0; ks < 4; ks++) {
      half8 bfr = *(const half8*)(&sW2[(nt * 16 + c) * 136 + ks * 32 + q * 8]);
      acc = __builtin_amdgcn_mfma_f32_16x16x32_f16(afr[ks], bfr, acc, 0, 0, 0);
    }
    int col = nt * 16 + c;
    float bb = fr2pv_b[col];
#pragma unroll
    for (int rg = 0; rg < 4; rg++) {
      int row = mbase + q * 4 + rg;
      sH[row * 136 + col] = (_Float16)fmaxf(acc[rg] + bb, 0.f);
    }
  }
  half8 a2[4];
#pragma unroll
  for (int ks = 0; ks < 4; ks++)
    a2[ks] = *(const half8*)(&sH[(mbase + c) * 136 + ks * 32 + q * 8]);
#pragma unroll
  for (int nt = 0; nt < 4; nt++) {
    floatx4 acc = {0.f, 0.f, 0.f, 0.f};
#pragma unroll
    for (int ks = 0; ks < 4; ks++) {
      half8 bfr = *(const half8*)(&W3T[(nt * 16 + c) * 128 + ks * 32 + q * 8]);
      acc = __builtin_amdgcn_mfma_f32_16x16x32_f16(a2[ks], bfr, acc, 0, 0, 0);
    }
    int col = nt * 16 + c;
    float bb = fr3pv_b[col];
#pragma unroll
    for (int rg = 0; rg < 4; rg++) {
      int row = mbase + q * 4 + rg;
      if (row < 56) {
        int kl = row / 14;
        float e = fmaxf(acc[rg] + bb, 0.f);
        atomicAdd(&sEacc[kl * 64 + col], e);
      }
    }
  }
  __syncthreads();
  if (tid < 256) {
    int kl = tid >> 6, col = tid & 63;
    Ebar[(b * NN + k0 + kl) * DE + col] = sEacc[tid];
  }
}

// ---------------- K3: node MLP + pool + classifier; block = batch ----------------
__global__ __launch_bounds__(256) void k3_out(
    const float* __restrict__ x, const float* __restrict__ Epp,
    const float* __restrict__ Epv,
    const float* __restrict__ fo1_b, const float* __restrict__ fo2_b,
    const float* __restrict__ fo3_b,
    const float* __restrict__ fc_w, const float* __restrict__ fc_b,
    const _Float16* __restrict__ fo1T, const _Float16* __restrict__ fo2T,
    const _Float16* __restrict__ fo3T,
    float* __restrict__ out) {
  __shared__ _Float16 sC[64 * 168];   // [n][160] padded
  __shared__ _Float16 sH[64 * 136];
  __shared__ float sPool[64];
  int tid = threadIdx.x;
  int b = blockIdx.x;
  if (tid < 64) sPool[tid] = 0.f;
  for (int i = tid; i < PP * NN; i += 256) {
    int p = i >> 6, n = i & 63;
    sC[n * 168 + p] = (_Float16)x[b * (PP * NN) + i];
  }
  for (int i = tid; i < NN * DE; i += 256) {
    int n = i >> 6, d = i & 63;
    sC[n * 168 + 32 + d] = (_Float16)Epp[b * (NN * DE) + i];
    sC[n * 168 + 96 + d] = (_Float16)Epv[b * (NN * DE) + i];
  }
  __syncthreads();
  int lane = tid & 63, wv = tid >> 6;
  int q = lane >> 4, c = lane & 15;
  int mbase = wv * 16;
  // fo1: K=160 (5 k-steps)
  half8 afr[5];
#pragma unroll
  for (int ks = 0; ks < 5; ks++)
    afr[ks] = *(const half8*)(&sC[(mbase + c) * 168 + ks * 32 + q * 8]);
#pragma unroll
  for (int nt = 0; nt < 8; nt++) {
    floatx4 acc = {0.f, 0.f, 0.f, 0.f};
#pragma unroll
    for (int ks = 0; ks < 5; ks++) {
      half8 bfr = *(const half8*)(&fo1T[(nt * 16 + c) * 160 + ks * 32 + q * 8]);
      acc = __builtin_amdgcn_mfma_f32_16x16x32_f16(afr[ks], bfr, acc, 0, 0, 0);
    }
    int col = nt * 16 + c;
    float bb = fo1_b[col];
#pragma unroll
    for (int rg = 0; rg < 4; rg++) {
      int row = mbase + q * 4 + rg;
      sH[row * 136 + col] = (_Float16)fmaxf(acc[rg] + bb, 0.f);
    }
  }
  // fo2
  half8 a2[4];
#pragma unroll
  for (int ks = 0; ks < 4; ks++)
    a2[ks] = *(const half8*)(&sH[(mbase + c) * 136 + ks * 32 + q * 8]);
#pragma unroll
  for (int nt = 0; nt < 8; nt++) {
    floatx4 acc = {0.f, 0.f, 0.f, 0.f};
#pragma unroll
    for (int ks = 0; ks < 4; ks++) {
      half8 bfr = *(const half8*)(&fo2T[(nt * 16 + c) * 128 + ks * 32 + q * 8]);
      acc = __builtin_amdgcn_mfma_f32_16x16x32_f16(a2[ks], bfr, acc, 0, 0, 0);
    }
    int col = nt * 16 + c;
    float bb = fo2_b[col];
#pragma unroll
    for (int rg = 0; rg < 4; rg++) {
      int row = mbase + q * 4 + rg;
      sH[row * 136 + col] = (_Float16)fmaxf(acc[rg] + bb, 0.f);
    }
  }
  // fo3 + pooled sum
  half8 a3[4];
#pragma unroll
  for (int ks = 0; ks < 4; ks++)
    a3[ks] = *(const half8*)(&sH[(mbase + c) * 136 + ks * 32 + q * 8]);
#pragma unroll
  for (int nt = 0; nt < 4; nt++) {
    floatx4 acc = {0.f, 0.f, 0.f, 0.f};
#pragma unroll
    for (int ks = 0; ks < 4; ks++) {
      half8 bfr = *(const half8*)(&fo3T[(nt * 16 + c) * 128 + ks * 32 + q * 8]);
      acc = __builtin_amdgcn_mfma_f32_16x16x32_f16(a3[ks], bfr, acc, 0, 0, 0);
    }
    int col = nt * 16 + c;
    float bb = fo3_b[col];
    float sum = 0.f;
#pragma unroll
    for (int rg = 0; rg < 4; rg++)
      sum += fmaxf(acc[rg] + bb, 0.f);
    sum += __shfl_xor(sum, 16);
    sum += __shfl_xor(sum, 32);
    if (lane < 16) atomicAdd(&sPool[col], sum);
  }
  __syncthreads();
  if (tid < NCLS) {
    float o = fc_b[tid];
#pragma unroll
    for (int d = 0; d < DO; d++) o += sPool[d] * fc_w[d * NCLS + tid];
    out[b * NCLS + tid] = o;
  }
}

extern "C" void kernel_launch(void* const* d_in, const int* in_sizes, int n_in,
                              void* d_out, int out_size, void* d_ws, size_t ws_size,
                              hipStream_t stream) {
  const float* x = (const float*)d_in[0];
  const float* y = (const float*)d_in[1];
  const float* fr1_w = (const float*)d_in[2];  const float* fr1_b = (const float*)d_in[3];
  const float* fr2_w = (const float*)d_in[4];  const float* fr2_b = (const float*)d_in[5];
  const float* fr3_w = (const float*)d_in[6];  const float* fr3_b = (const float*)d_in[7];
  const float* fr1pv_w = (const float*)d_in[8];  const float* fr1pv_b = (const float*)d_in[9];
  const float* fr2pv_w = (const float*)d_in[10]; const float* fr2pv_b = (const float*)d_in[11];
  const float* fr3pv_w = (const float*)d_in[12]; const float* fr3pv_b = (const float*)d_in[13];
  const float* fo1_w = (const float*)d_in[14];  const float* fo1_b = (const float*)d_in[15];
  const float* fo2_w = (const float*)d_in[16];  const float* fo2_b = (const float*)d_in[17];
  const float* fo3_w = (const float*)d_in[18];  const float* fo3_b = (const float*)d_in[19];
  const float* fc_w = (const float*)d_in[20];   const float* fc_b = (const float*)d_in[21];

  char* ws = (char*)d_ws;
  float* A1   = (float*)(ws);                    // [128][64][128] f32, 4 MB
  float* B1   = (float*)(ws + (4u << 20));       // 4 MB
  float* A1pv = (float*)(ws + (8u << 20));       // 4 MB
  float* B1pv = (float*)(ws + (12u << 20));      // [128][14][128] f32
  float* Epp  = (float*)(ws + (13u << 20));      // [128][64][64] f32, 2 MB
  float* Epv  = (float*)(ws + (15u << 20));      // 2 MB
  _Float16* WT = (_Float16*)(ws + (17u << 20));  // transposed fp16 weights

  k0_prep<<<NB + 7, 256, 0, stream>>>(x, y, fr1_w, fr1pv_w, fr2_w, fr3_w,
                                      fr2pv_w, fr3pv_w, fo1_w, fo2_w, fo3_w,
                                      A1, B1, A1pv, B1pv, WT);
  k1_pp<<<NB * NN, 256, 0, stream>>>(A1, B1, fr1_b, fr2_b, fr3_b,
                                     WT + OFF_W2T, WT + OFF_W3T, Epp);
  k2_pv<<<NB * 16, 256, 0, stream>>>(A1pv, B1pv, fr1pv_b, fr2pv_b, fr3pv_b,
                                     WT + OFF_W2PVT, WT + OFF_W3PVT, Epv);
  k3_out<<<NB, 256, 0, stream>>>(x, Epp, Epv, fo1_b, fo2_b, fo3_b, fc_w, fc_b,
                                 WT + OFF_FO1T, WT + OFF_FO2T, WT + OFF_FO3T,
                                 (float*)d_out);
}

// Round 2
// 244.000 us; speedup vs baseline: 1.2786x; 1.2786x over previous
//
#include <hip/hip_runtime.h>

typedef __attribute__((ext_vector_type(8))) _Float16 half8;
typedef __attribute__((ext_vector_type(4))) _Float16 half4v;
typedef __attribute__((ext_vector_type(4))) float floatx4;

#define NB 128
#define NN 64
#define NV 14
#define PP 32
#define SS 14
#define HH 128
#define DE 64
#define NCLS 5

// WT element offsets (fp16 units)
#define OFF_W2T   0
#define OFF_W3T   16384
#define OFF_W2PVT 24576
#define OFF_W3PVT 40960
#define OFF_FO1T  49152
#define OFF_FO2T  69632
#define OFF_FO3T  86016

// pitch 136 fp16 = 272 B = 16*17 -> keeps half8/uint4 LDS ops 16B-aligned
#define PITCH 136

// ---------------- K0: per-node layer-1 terms, weight transpose/fp16, d_out zero ----------------
__global__ __launch_bounds__(256) void k0_prep(
    const float* __restrict__ x, const float* __restrict__ y,
    const float* __restrict__ fr1_w, const float* __restrict__ fr1pv_w,
    const float* __restrict__ fr2_w, const float* __restrict__ fr3_w,
    const float* __restrict__ fr2pv_w, const float* __restrict__ fr3pv_w,
    const float* __restrict__ fo1_w, const float* __restrict__ fo2_w,
    const float* __restrict__ fo3_w,
    float* __restrict__ A1, float* __restrict__ B1,
    float* __restrict__ A1pv, float* __restrict__ B1pv,
    _Float16* __restrict__ WT, float* __restrict__ dout) {
  int blk = blockIdx.x;
  int tid = threadIdx.x;
  if (blk < 384) {
    // one (matrix, batch) per block: A1 / B1 / A1pv, each 64x128, K=32
    int mat = blk >> 7, b = blk & 127;
    __shared__ float sxT[NN * 33];
    for (int i = tid; i < NN * PP; i += 256) {
      int p = i >> 6, n = i & 63;
      sxT[n * 33 + p] = x[b * (PP * NN) + i];
    }
    __syncthreads();
    const float* w = (mat == 0) ? fr1_w : (mat == 1) ? (fr1_w + 32 * HH) : fr1pv_w;
    float* outp = (mat == 0) ? A1 : (mat == 1) ? B1 : A1pv;
    for (int o = tid; o < NN * 32; o += 256) {
      int n = o >> 5, jc = o & 31;
      float4 acc = {0.f, 0.f, 0.f, 0.f};
      const float* xr = &sxT[n * 33];
#pragma unroll 8
      for (int k = 0; k < PP; k++) {
        float xv = xr[k];
        float4 wv = ((const float4*)w)[k * 32 + jc];
        acc.x += xv * wv.x; acc.y += xv * wv.y;
        acc.z += xv * wv.z; acc.w += xv * wv.w;
      }
      ((float4*)outp)[(b * NN + n) * 32 + jc] = acc;
    }
  } else if (blk < 512) {
    // B1pv: yT(14x14) @ fr1pv_w[32:46] -> [b][14][128]
    int b = blk - 384;
    __shared__ float syT[NV * 15];
    for (int i = tid; i < SS * NV; i += 256) {
      int s = i / NV, v = i - s * NV;
      syT[v * 15 + s] = y[b * (SS * NV) + i];
    }
    __syncthreads();
    const float4* w4 = (const float4*)(fr1pv_w + 32 * HH);
    for (int o = tid; o < NV * 32; o += 256) {
      int v = o >> 5, jc = o & 31;
      float4 acc = {0.f, 0.f, 0.f, 0.f};
#pragma unroll
      for (int s = 0; s < SS; s++) {
        float yv = syT[v * 15 + s];
        float4 wv = w4[s * 32 + jc];
        acc.x += yv * wv.x; acc.y += yv * wv.y;
        acc.z += yv * wv.z; acc.w += yv * wv.w;
      }
      ((float4*)B1pv)[(b * NV + v) * 32 + jc] = acc;
    }
  } else if (blk < 519) {
    // transpose + fp16 convert weights: dst[n][k] = src[k][n]
    int wid = blk - 512;
    const float* src; int K, N; _Float16* dst;
    switch (wid) {
      case 0: src = fr2_w;   K = 128; N = 128; dst = WT + OFF_W2T;   break;
      case 1: src = fr3_w;   K = 128; N = 64;  dst = WT + OFF_W3T;   break;
      case 2: src = fr2pv_w; K = 128; N = 128; dst = WT + OFF_W2PVT; break;
      case 3: src = fr3pv_w; K = 128; N = 64;  dst = WT + OFF_W3PVT; break;
      case 4: src = fo1_w;   K = 160; N = 128; dst = WT + OFF_FO1T;  break;
      case 5: src = fo2_w;   K = 128; N = 128; dst = WT + OFF_FO2T;  break;
      default: src = fo3_w;  K = 128; N = 64;  dst = WT + OFF_FO3T;  break;
    }
    int tot = K * N;
    for (int i = tid; i < tot; i += 256) {
      int n = i / K, k = i - n * K;
      dst[i] = (_Float16)src[k * N + n];
    }
  } else {
    for (int i = tid; i < NB * NCLS; i += 256) dout[i] = 0.f;
  }
}

// ---------------- K1: pp edges. block = (b, 8 receivers) = 504 rows, 4 chunks x 128.
// Layer2 in transposed-C orientation: each wave writes ONLY its own 32 sH rows ->
// no __syncthreads in the main loop (within-wave DS ops are in program order).
__global__ __launch_bounds__(256, 2) void k1_pp(
    const float* __restrict__ A1, const float* __restrict__ B1,
    const float* __restrict__ fr1_b, const float* __restrict__ fr2_b,
    const float* __restrict__ fr3_b,
    const _Float16* __restrict__ W2T, const _Float16* __restrict__ W3T,
    float* __restrict__ Ebar) {
  __shared__ _Float16 sW2[128 * PITCH];   // 34816 B
  __shared__ _Float16 sH[128 * PITCH];    // 34816 B (chunk h2, wave-partitioned rows)
  __shared__ float sA1f[8 * 128];         // A1[r]+b1 for the block's 8 receivers
  __shared__ float sEb[8 * 64];
  int tid = threadIdx.x;
  int b = blockIdx.x >> 3, r0 = (blockIdx.x & 7) << 3;
  for (int i = tid; i < 512; i += 256) sEb[i] = 0.f;
  for (int i = tid; i < 2048; i += 256) {
    int row = i >> 4, cc = i & 15;
    *(uint4*)(&sW2[row * PITCH + cc * 8]) = *(const uint4*)(&W2T[row * 128 + cc * 8]);
  }
  for (int i = tid; i < 1024; i += 256) {
    int rr = i >> 7, k = i & 127;
    sA1f[i] = A1[(b * NN + r0 + rr) * HH + k] + fr1_b[k];
  }
  int lane = tid & 63, wv = tid >> 6;
  int c = lane & 15, q = lane >> 4;
  // hoist W3 fragments + layer3 bias for the whole block
  half8 w3f[4][4];
  float bias3[4];
#pragma unroll
  for (int nt = 0; nt < 4; nt++) {
    bias3[nt] = fr3_b[nt * 16 + c];
#pragma unroll
    for (int ks = 0; ks < 4; ks++)
      w3f[nt][ks] = *(const half8*)(&W3T[(nt * 16 + c) * 128 + ks * 32 + q * 8]);
  }
  __syncthreads();
  const float* B1b = B1 + b * NN * HH;
#pragma unroll
  for (int ch = 0; ch < 4; ch++) {
    int wrow = wv * 32;                 // chunk-local wave row base
    int rowbase = ch * 128 + wrow;      // block-local
    // ---- build h1 fragments (B-operand layout) directly in registers ----
    half8 hf[2][4];
#pragma unroll
    for (int mt = 0; mt < 2; mt++) {
      int rl = rowbase + mt * 16 + c;
      bool valid = rl < 504;
      int rr = rl / 63; if (rr > 7) rr = 7;
      int jj = rl - rr * 63;
      int r = r0 + rr;
      int s = jj + (jj >= r ? 1 : 0); if (s > 63) s = 0;
      const float* bp = B1b + s * HH;
      const float* ap = sA1f + rr * 128;
#pragma unroll
      for (int ks = 0; ks < 4; ks++) {
        half8 h = {};
        if (valid) {
          float4 x0 = *(const float4*)(bp + ks * 32 + q * 8);
          float4 x1 = *(const float4*)(bp + ks * 32 + q * 8 + 4);
          float4 y0 = *(const float4*)(ap + ks * 32 + q * 8);
          float4 y1 = *(const float4*)(ap + ks * 32 + q * 8 + 4);
          h[0] = (_Float16)fmaxf(x0.x + y0.x, 0.f);
          h[1] = (_Float16)fmaxf(x0.y + y0.y, 0.f);
          h[2] = (_Float16)fmaxf(x0.z + y0.z, 0.f);
          h[3] = (_Float16)fmaxf(x0.w + y0.w, 0.f);
          h[4] = (_Float16)fmaxf(x1.x + y1.x, 0.f);
          h[5] = (_Float16)fmaxf(x1.y + y1.y, 0.f);
          h[6] = (_Float16)fmaxf(x1.z + y1.z, 0.f);
          h[7] = (_Float16)fmaxf(x1.w + y1.w, 0.f);
        }
        hf[mt][ks] = h;
      }
    }
    // ---- layer2: h2^T = W2^T x h1^T (A = W2 frag, B = h1 frag) ----
#pragma unroll
    for (int nt = 0; nt < 8; nt++) {
      floatx4 a0 = {0.f, 0.f, 0.f, 0.f}, a1 = {0.f, 0.f, 0.f, 0.f};
#pragma unroll
      for (int ks = 0; ks < 4; ks++) {
        half8 wf = *(const half8*)(&sW2[(nt * 16 + c) * PITCH + ks * 32 + q * 8]);
        a0 = __builtin_amdgcn_mfma_f32_16x16x32_f16(wf, hf[0][ks], a0, 0, 0, 0);
        a1 = __builtin_amdgcn_mfma_f32_16x16x32_f16(wf, hf[1][ks], a1, 0, 0, 0);
      }
      float4 bb = *(const float4*)(&fr2_b[nt * 16 + q * 4]);
      half4v h0, h1v;
      h0[0] = (_Float16)fmaxf(a0[0] + bb.x, 0.f);
      h0[1] = (_Float16)fmaxf(a0[1] + bb.y, 0.f);
      h0[2] = (_Float16)fmaxf(a0[2] + bb.z, 0.f);
      h0[3] = (_Float16)fmaxf(a0[3] + bb.w, 0.f);
      h1v[0] = (_Float16)fmaxf(a1[0] + bb.x, 0.f);
      h1v[1] = (_Float16)fmaxf(a1[1] + bb.y, 0.f);
      h1v[2] = (_Float16)fmaxf(a1[2] + bb.z, 0.f);
      h1v[3] = (_Float16)fmaxf(a1[3] + bb.w, 0.f);
      *(half4v*)(&sH[(wrow + c) * PITCH + nt * 16 + q * 4]) = h0;
      *(half4v*)(&sH[(wrow + 16 + c) * PITCH + nt * 16 + q * 4]) = h1v;
    }
    // ---- layer3: E = h2 @ W3 (A = h2 frag from own rows, B = hoisted W3 frag) ----
    half8 a2[2][4];
#pragma unroll
    for (int mt = 0; mt < 2; mt++)
#pragma unroll
      for (int ks = 0; ks < 4; ks++)
        a2[mt][ks] = *(const half8*)(&sH[(wrow + mt * 16 + c) * PITCH + ks * 32 + q * 8]);
#pragma unroll
    for (int nt = 0; nt < 4; nt++) {
      floatx4 e0 = {0.f, 0.f, 0.f, 0.f}, e1 = {0.f, 0.f, 0.f, 0.f};
#pragma unroll
      for (int ks = 0; ks < 4; ks++) {
        e0 = __builtin_amdgcn_mfma_f32_16x16x32_f16(a2[0][ks], w3f[nt][ks], e0, 0, 0, 0);
        e1 = __builtin_amdgcn_mfma_f32_16x16x32_f16(a2[1][ks], w3f[nt][ks], e1, 0, 0, 0);
      }
      int col = nt * 16 + c;
      float bb = bias3[nt];
#pragma unroll
      for (int mt = 0; mt < 2; mt++) {
        floatx4 ac = mt ? e1 : e0;
        int rbase = ch * 128 + wrow + mt * 16 + q * 4;
        if (rbase < 504) {
          float v0 = fmaxf(ac[0] + bb, 0.f);
          float v1 = fmaxf(ac[1] + bb, 0.f);
          float v2 = fmaxf(ac[2] + bb, 0.f);
          float v3 = fmaxf(ac[3] + bb, 0.f);
          int rrA = rbase / 63;
          int rrB = (rbase + 3) / 63;
          if (rrA == rrB && rbase + 3 < 504) {
            atomicAdd(&sEb[rrA * 64 + col], v0 + v1 + v2 + v3);
          } else {
            float vs[4] = {v0, v1, v2, v3};
            for (int rg = 0; rg < 4; rg++) {
              int rr2 = rbase + rg;
              if (rr2 < 504) atomicAdd(&sEb[(rr2 / 63) * 64 + col], vs[rg]);
            }
          }
        }
      }
    }
  }
  __syncthreads();
  for (int i = tid; i < 512; i += 256)
    Ebar[(b * NN + r0 + (i >> 6)) * DE + (i & 63)] = sEb[i];
}

// ---------------- K2: pv edges. block = (b, 16 k-nodes) = 224 rows, 2 chunks x 128 ----------------
__global__ __launch_bounds__(256, 2) void k2_pv(
    const float* __restrict__ A1pv, const float* __restrict__ B1pv,
    const float* __restrict__ fr1pv_b, const float* __restrict__ fr2pv_b,
    const float* __restrict__ fr3pv_b,
    const _Float16* __restrict__ W2T, const _Float16* __restrict__ W3T,
    float* __restrict__ Ebar) {
  __shared__ _Float16 sW2[128 * PITCH];
  __shared__ _Float16 sH[128 * PITCH];
  __shared__ float sAf[16 * 128];
  __shared__ float sEb[16 * 64];
  int tid = threadIdx.x;
  int b = blockIdx.x >> 2, k0g = (blockIdx.x & 3) << 4;
  for (int i = tid; i < 1024; i += 256) sEb[i] = 0.f;
  for (int i = tid; i < 2048; i += 256) {
    int row = i >> 4, cc = i & 15;
    *(uint4*)(&sW2[row * PITCH + cc * 8]) = *(const uint4*)(&W2T[row * 128 + cc * 8]);
  }
  for (int i = tid; i < 2048; i += 256) {
    int rr = i >> 7, k = i & 127;
    sAf[i] = A1pv[(b * NN + k0g + rr) * HH + k] + fr1pv_b[k];
  }
  int lane = tid & 63, wv = tid >> 6;
  int c = lane & 15, q = lane >> 4;
  half8 w3f[4][4];
  float bias3[4];
#pragma unroll
  for (int nt = 0; nt < 4; nt++) {
    bias3[nt] = fr3pv_b[nt * 16 + c];
#pragma unroll
    for (int ks = 0; ks < 4; ks++)
      w3f[nt][ks] = *(const half8*)(&W3T[(nt * 16 + c) * 128 + ks * 32 + q * 8]);
  }
  __syncthreads();
  const float* Bb = B1pv + b * NV * HH;
#pragma unroll
  for (int ch = 0; ch < 2; ch++) {
    int wrow = wv * 32;
    int rowbase = ch * 128 + wrow;
    half8 hf[2][4];
#pragma unroll
    for (int mt = 0; mt < 2; mt++) {
      int rl = rowbase + mt * 16 + c;
      bool valid = rl < 224;
      int rr = rl / 14; if (rr > 15) rr = 15;
      int v = rl - rr * 14; if (v > 13) v = 0;
      const float* bp = Bb + v * HH;
      const float* ap = sAf + rr * 128;
#pragma unroll
      for (int ks = 0; ks < 4; ks++) {
        half8 h = {};
        if (valid) {
          float4 x0 = *(const float4*)(bp + ks * 32 + q * 8);
          float4 x1 = *(const float4*)(bp + ks * 32 + q * 8 + 4);
          float4 y0 = *(const float4*)(ap + ks * 32 + q * 8);
          float4 y1 = *(const float4*)(ap + ks * 32 + q * 8 + 4);
          h[0] = (_Float16)fmaxf(x0.x + y0.x, 0.f);
          h[1] = (_Float16)fmaxf(x0.y + y0.y, 0.f);
          h[2] = (_Float16)fmaxf(x0.z + y0.z, 0.f);
          h[3] = (_Float16)fmaxf(x0.w + y0.w, 0.f);
          h[4] = (_Float16)fmaxf(x1.x + y1.x, 0.f);
          h[5] = (_Float16)fmaxf(x1.y + y1.y, 0.f);
          h[6] = (_Float16)fmaxf(x1.z + y1.z, 0.f);
          h[7] = (_Float16)fmaxf(x1.w + y1.w, 0.f);
        }
        hf[mt][ks] = h;
      }
    }
#pragma unroll
    for (int nt = 0; nt < 8; nt++) {
      floatx4 a0 = {0.f, 0.f, 0.f, 0.f}, a1 = {0.f, 0.f, 0.f, 0.f};
#pragma unroll
      for (int ks = 0; ks < 4; ks++) {
        half8 wf = *(const half8*)(&sW2[(nt * 16 + c) * PITCH + ks * 32 + q * 8]);
        a0 = __builtin_amdgcn_mfma_f32_16x16x32_f16(wf, hf[0][ks], a0, 0, 0, 0);
        a1 = __builtin_amdgcn_mfma_f32_16x16x32_f16(wf, hf[1][ks], a1, 0, 0, 0);
      }
      float4 bb = *(const float4*)(&fr2pv_b[nt * 16 + q * 4]);
      half4v h0, h1v;
      h0[0] = (_Float16)fmaxf(a0[0] + bb.x, 0.f);
      h0[1] = (_Float16)fmaxf(a0[1] + bb.y, 0.f);
      h0[2] = (_Float16)fmaxf(a0[2] + bb.z, 0.f);
      h0[3] = (_Float16)fmaxf(a0[3] + bb.w, 0.f);
      h1v[0] = (_Float16)fmaxf(a1[0] + bb.x, 0.f);
      h1v[1] = (_Float16)fmaxf(a1[1] + bb.y, 0.f);
      h1v[2] = (_Float16)fmaxf(a1[2] + bb.z, 0.f);
      h1v[3] = (_Float16)fmaxf(a1[3] + bb.w, 0.f);
      *(half4v*)(&sH[(wrow + c) * PITCH + nt * 16 + q * 4]) = h0;
      *(half4v*)(&sH[(wrow + 16 + c) * PITCH + nt * 16 + q * 4]) = h1v;
    }
    half8 a2[2][4];
#pragma unroll
    for (int mt = 0; mt < 2; mt++)
#pragma unroll
      for (int ks = 0; ks < 4; ks++)
        a2[mt][ks] = *(const half8*)(&sH[(wrow + mt * 16 + c) * PITCH + ks * 32 + q * 8]);
#pragma unroll
    for (int nt = 0; nt < 4; nt++) {
      floatx4 e0 = {0.f, 0.f, 0.f, 0.f}, e1 = {0.f, 0.f, 0.f, 0.f};
#pragma unroll
      for (int ks = 0; ks < 4; ks++) {
        e0 = __builtin_amdgcn_mfma_f32_16x16x32_f16(a2[0][ks], w3f[nt][ks], e0, 0, 0, 0);
        e1 = __builtin_amdgcn_mfma_f32_16x16x32_f16(a2[1][ks], w3f[nt][ks], e1, 0, 0, 0);
      }
      int col = nt * 16 + c;
      float bb = bias3[nt];
#pragma unroll
      for (int mt = 0; mt < 2; mt++) {
        floatx4 ac = mt ? e1 : e0;
        int rbase = ch * 128 + wrow + mt * 16 + q * 4;
        if (rbase < 224) {
          float v0 = fmaxf(ac[0] + bb, 0.f);
          float v1 = fmaxf(ac[1] + bb, 0.f);
          float v2 = fmaxf(ac[2] + bb, 0.f);
          float v3 = fmaxf(ac[3] + bb, 0.f);
          int rrA = rbase / 14;
          int rrB = (rbase + 3) / 14;
          if (rrA == rrB && rbase + 3 < 224) {
            atomicAdd(&sEb[rrA * 64 + col], v0 + v1 + v2 + v3);
          } else {
            float vs[4] = {v0, v1, v2, v3};
            for (int rg = 0; rg < 4; rg++) {
              int rr2 = rbase + rg;
              if (rr2 < 224) atomicAdd(&sEb[(rr2 / 14) * 64 + col], vs[rg]);
            }
          }
        }
      }
    }
  }
  __syncthreads();
  for (int i = tid; i < 1024; i += 256)
    Ebar[(b * NN + k0g + (i >> 6)) * DE + (i & 63)] = sEb[i];
}

// ---------------- K3: node MLP + pool + fc; block = (batch, half of nodes) ----------------
__global__ __launch_bounds__(256) void k3_out(
    const float* __restrict__ x, const float* __restrict__ Epp,
    const float* __restrict__ Epv,
    const float* __restrict__ fo1_b, const float* __restrict__ fo2_b,
    const float* __restrict__ fo3_b,
    const float* __restrict__ fc_w, const float* __restrict__ fc_b,
    const _Float16* __restrict__ fo1T, const _Float16* __restrict__ fo2T,
    const _Float16* __restrict__ fo3T,
    float* __restrict__ out) {
  __shared__ _Float16 sC[32 * 168];
  __shared__ _Float16 sH1[32 * PITCH];
  __shared__ _Float16 sH2[32 * PITCH];
  __shared__ float sPool[64];
  int tid = threadIdx.x;
  int b = blockIdx.x >> 1, hh = blockIdx.x & 1;
  int n0 = hh * 32;
  for (int i = tid; i < 32 * 32; i += 256) {
    int p = i >> 5, n = i & 31;
    sC[n * 168 + p] = (_Float16)x[b * (PP * NN) + p * 64 + n0 + n];
  }
  for (int i = tid; i < 32 * 64; i += 256) {
    int n = i >> 6, d = i & 63;
    sC[n * 168 + 32 + d] = (_Float16)Epp[(b * NN + n0 + n) * DE + d];
    sC[n * 168 + 96 + d] = (_Float16)Epv[(b * NN + n0 + n) * DE + d];
  }
  __syncthreads();
  int lane = tid & 63, wv = tid >> 6;
  int c = lane & 15, q = lane >> 4;
  // fo1 (K=160), transposed-C; wave owns 32 output cols
  half8 cf[2][5];
#pragma unroll
  for (int mt = 0; mt < 2; mt++)
#pragma unroll
    for (int ks = 0; ks < 5; ks++)
      cf[mt][ks] = *(const half8*)(&sC[(mt * 16 + c) * 168 + ks * 32 + q * 8]);
#pragma unroll
  for (int nt2 = 0; nt2 < 2; nt2++) {
    int n = (wv * 2 + nt2) * 16;
    floatx4 a0 = {0.f, 0.f, 0.f, 0.f}, a1 = {0.f, 0.f, 0.f, 0.f};
#pragma unroll
    for (int ks = 0; ks < 5; ks++) {
      half8 wf = *(const half8*)(&fo1T[(n + c) * 160 + ks * 32 + q * 8]);
      a0 = __builtin_amdgcn_mfma_f32_16x16x32_f16(wf, cf[0][ks], a0, 0, 0, 0);
      a1 = __builtin_amdgcn_mfma_f32_16x16x32_f16(wf, cf[1][ks], a1, 0, 0, 0);
    }
    float4 bb = *(const float4*)(&fo1_b[n + q * 4]);
    half4v h0, h1v;
    h0[0] = (_Float16)fmaxf(a0[0] + bb.x, 0.f);
    h0[1] = (_Float16)fmaxf(a0[1] + bb.y, 0.f);
    h0[2] = (_Float16)fmaxf(a0[2] + bb.z, 0.f);
    h0[3] = (_Float16)fmaxf(a0[3] + bb.w, 0.f);
    h1v[0] = (_Float16)fmaxf(a1[0] + bb.x, 0.f);
    h1v[1] = (_Float16)fmaxf(a1[1] + bb.y, 0.f);
    h1v[2] = (_Float16)fmaxf(a1[2] + bb.z, 0.f);
    h1v[3] = (_Float16)fmaxf(a1[3] + bb.w, 0.f);
    *(half4v*)(&sH1[(c) * PITCH + n + q * 4]) = h0;
    *(half4v*)(&sH1[(16 + c) * PITCH + n + q * 4]) = h1v;
  }
  __syncthreads();
  // fo2 (K=128), transposed-C
  half8 hf[2][4];
#pragma unroll
  for (int mt = 0; mt < 2; mt++)
#pragma unroll
    for (int ks = 0; ks < 4; ks++)
      hf[mt][ks] = *(const half8*)(&sH1[(mt * 16 + c) * PITCH + ks * 32 + q * 8]);
#pragma unroll
  for (int nt2 = 0; nt2 < 2; nt2++) {
    int n = (wv * 2 + nt2) * 16;
    floatx4 a0 = {0.f, 0.f, 0.f, 0.f}, a1 = {0.f, 0.f, 0.f, 0.f};
#pragma unroll
    for (int ks = 0; ks < 4; ks++) {
      half8 wf = *(const half8*)(&fo2T[(n + c) * 128 + ks * 32 + q * 8]);
      a0 = __builtin_amdgcn_mfma_f32_16x16x32_f16(wf, hf[0][ks], a0, 0, 0, 0);
      a1 = __builtin_amdgcn_mfma_f32_16x16x32_f16(wf, hf[1][ks], a1, 0, 0, 0);
    }
    float4 bb = *(const float4*)(&fo2_b[n + q * 4]);
    half4v h0, h1v;
    h0[0] = (_Float16)fmaxf(a0[0] + bb.x, 0.f);
    h0[1] = (_Float16)fmaxf(a0[1] + bb.y, 0.f);
    h0[2] = (_Float16)fmaxf(a0[2] + bb.z, 0.f);
    h0[3] = (_Float16)fmaxf(a0[3] + bb.w, 0.f);
    h1v[0] = (_Float16)fmaxf(a1[0] + bb.x, 0.f);
    h1v[1] = (_Float16)fmaxf(a1[1] + bb.y, 0.f);
    h1v[2] = (_Float16)fmaxf(a1[2] + bb.z, 0.f);
    h1v[3] = (_Float16)fmaxf(a1[3] + bb.w, 0.f);
    *(half4v*)(&sH2[(c) * PITCH + n + q * 4]) = h0;
    *(half4v*)(&sH2[(16 + c) * PITCH + n + q * 4]) = h1v;
  }
  __syncthreads();
  // fo3 (N=64), original orientation; wave owns 16 cols; pool over 32 rows
  half8 g[2][4];
#pragma unroll
  for (int mt = 0; mt < 2; mt++)
#pragma unroll
    for (int ks = 0; ks < 4; ks++)
      g[mt][ks] = *(const half8*)(&sH2[(mt * 16 + c) * PITCH + ks * 32 + q * 8]);
  floatx4 e0 = {0.f, 0.f, 0.f, 0.f}, e1 = {0.f, 0.f, 0.f, 0.f};
#pragma unroll
  for (int ks = 0; ks < 4; ks++) {
    half8 wf = *(const half8*)(&fo3T[(wv * 16 + c) * 128 + ks * 32 + q * 8]);
    e0 = __builtin_amdgcn_mfma_f32_16x16x32_f16(g[0][ks], wf, e0, 0, 0, 0);
    e1 = __builtin_amdgcn_mfma_f32_16x16x32_f16(g[1][ks], wf, e1, 0, 0, 0);
  }
  float bb3 = fo3_b[wv * 16 + c];
  float s = 0.f;
#pragma unroll
  for (int rg = 0; rg < 4; rg++)
    s += fmaxf(e0[rg] + bb3, 0.f) + fmaxf(e1[rg] + bb3, 0.f);
  s += __shfl_xor(s, 16);
  s += __shfl_xor(s, 32);
  if (lane < 16) sPool[wv * 16 + c] = s;
  __syncthreads();
  if (tid < NCLS) {
    float o = 0.f;
#pragma unroll
    for (int d = 0; d < 64; d++) o += sPool[d] * fc_w[d * NCLS + tid];
    if (hh == 0) o += fc_b[tid];
    atomicAdd(&out[b * NCLS + tid], o);
  }
}

extern "C" void kernel_launch(void* const* d_in, const int* in_sizes, int n_in,
                              void* d_out, int out_size, void* d_ws, size_t ws_size,
                              hipStream_t stream) {
  const float* x = (const float*)d_in[0];
  const float* y = (const float*)d_in[1];
  const float* fr1_w = (const float*)d_in[2];  const float* fr1_b = (const float*)d_in[3];
  const float* fr2_w = (const float*)d_in[4];  const float* fr2_b = (const float*)d_in[5];
  const float* fr3_w = (const float*)d_in[6];  const float* fr3_b = (const float*)d_in[7];
  const float* fr1pv_w = (const float*)d_in[8];  const float* fr1pv_b = (const float*)d_in[9];
  const float* fr2pv_w = (const float*)d_in[10]; const float* fr2pv_b = (const float*)d_in[11];
  const float* fr3pv_w = (const float*)d_in[12]; const float* fr3pv_b = (const float*)d_in[13];
  const float* fo1_w = (const float*)d_in[14];  const float* fo1_b = (const float*)d_in[15];
  const float* fo2_w = (const float*)d_in[16];  const float* fo2_b = (const float*)d_in[17];
  const float* fo3_w = (const float*)d_in[18];  const float* fo3_b = (const float*)d_in[19];
  const float* fc_w = (const float*)d_in[20];   const float* fc_b = (const float*)d_in[21];

  char* ws = (char*)d_ws;
  float* A1   = (float*)(ws);                    // [128][64][128] f32, 4 MB
  float* B1   = (float*)(ws + (4u << 20));
  float* A1pv = (float*)(ws + (8u << 20));
  float* B1pv = (float*)(ws + (12u << 20));      // [128][14][128] f32
  float* Epp  = (float*)(ws + (13u << 20));      // [128][64][64] f32, 2 MB
  float* Epv  = (float*)(ws + (15u << 20));
  _Float16* WT = (_Float16*)(ws + (17u << 20));

  k0_prep<<<520, 256, 0, stream>>>(x, y, fr1_w, fr1pv_w, fr2_w, fr3_w,
                                   fr2pv_w, fr3pv_w, fo1_w, fo2_w, fo3_w,
                                   A1, B1, A1pv, B1pv, WT, (float*)d_out);
  k1_pp<<<NB * 8, 256, 0, stream>>>(A1, B1, fr1_b, fr2_b, fr3_b,
                                    WT + OFF_W2T, WT + OFF_W3T, Epp);
  k2_pv<<<NB * 4, 256, 0, stream>>>(A1pv, B1pv, fr1pv_b, fr2pv_b, fr3pv_b,
                                    WT + OFF_W2PVT, WT + OFF_W3PVT, Epv);
  k3_out<<<NB * 2, 256, 0, stream>>>(x, Epp, Epv, fo1_b, fo2_b, fo3_b, fc_w, fc_b,
                                     WT + OFF_FO1T, WT + OFF_FO2T, WT + OFF_FO3T,
                                     (float*)d_out);
}